// Round 1
// baseline (172.556 us; speedup 1.0000x reference)
//
#include <hip/hip_runtime.h>
#include <math.h>

#define IN_CH 128
#define OUT_CH 64
#define NEG_SLOPE 0.2f
#define CAP 64   // slots per node; mean degree 16, P(deg>64) ~ 1e-16 for uniform dst
#define EPT 4    // edges per thread (count+scatter), fused into every block

typedef long long ll2 __attribute__((ext_vector_type(2)));
typedef int i4v __attribute__((ext_vector_type(4)));

// ---------- bf16 helpers ----------
__device__ __forceinline__ unsigned short f2bf(float f) {
    unsigned u = __float_as_uint(f);
    unsigned r = (u + 0x7FFFu + ((u >> 16) & 1u)) >> 16;   // round-nearest-even
    return (unsigned short)r;
}

// ---------- edge dtype sniff: int64 little-endian => odd int32 words are 0 ----------
__device__ __forceinline__ bool sniff_is64(const void* edges) {
    const unsigned* up = (const unsigned*)edges;
    bool is64 = true;
#pragma unroll
    for (int k = 0; k < 16; k++) is64 = is64 && (up[2 * k + 1] == 0u);
    return is64;
}

// ---------- K1 fused: every block = 1024-edge count+scatter UNDER a 64-node mm tile ----
// Old structure (role-split blocks) was latency-starved on the 800K device-scope
// atomicAdd round trips (~800cy to home-XCD L2): only ~40 atomics in flight per CU.
// New structure: issue edge loads (nt) + count atomics FIRST (fire-and-forget; results
// consumed only at the very end), run the mm tile while they complete, then do the
// slot scatter-stores. Also: W is read straight from global (L1/L2-resident 32KB
// broadcast) instead of LDS staging -> LDS_Block_Size 0 -> no 5-blocks/CU cap.
__global__ __launch_bounds__(256) void k_mm_cs(
        const float* __restrict__ x, const float* __restrict__ W,
        const float* __restrict__ att, unsigned short* __restrict__ h16,
        float* __restrict__ asrc, float* __restrict__ adst, int N,
        const void* __restrict__ edges, int* __restrict__ counts,
        int* __restrict__ slots, int* __restrict__ oflow_cnt,
        int2* __restrict__ oflow, int E) {
    int t = threadIdx.x;
    int bid = blockIdx.x;

    // ---------- phase 1: edge loads (non-temporal) + count atomics ----------
    // nt keeps the streaming edge columns out of L2 so they can't evict the slot
    // region mid-accumulation (R12 evidence from previous session).
    int e0 = (bid * 256 + t) * EPT;
    int s[EPT], d[EPT], r[EPT];
    bool fullcs = (e0 + EPT <= E);
    if (fullcs) {
        if (sniff_is64(edges)) {
            const ll2* ps = (const ll2*)((const long long*)edges + e0);
            const ll2* pd = (const ll2*)((const long long*)edges + (size_t)E + e0);
            ll2 v0 = __builtin_nontemporal_load(ps);
            ll2 v1 = __builtin_nontemporal_load(ps + 1);
            ll2 w0 = __builtin_nontemporal_load(pd);
            ll2 w1 = __builtin_nontemporal_load(pd + 1);
            s[0] = (int)v0.x; s[1] = (int)v0.y; s[2] = (int)v1.x; s[3] = (int)v1.y;
            d[0] = (int)w0.x; d[1] = (int)w0.y; d[2] = (int)w1.x; d[3] = (int)w1.y;
        } else {
            i4v v = __builtin_nontemporal_load((const i4v*)((const int*)edges + e0));
            i4v w = __builtin_nontemporal_load((const i4v*)((const int*)edges + E + e0));
            s[0] = v.x; s[1] = v.y; s[2] = v.z; s[3] = v.w;
            d[0] = w.x; d[1] = w.y; d[2] = w.z; d[3] = w.w;
        }
#pragma unroll
        for (int i = 0; i < EPT; i++) r[i] = atomicAdd(counts + d[i], 1);
    } else if (e0 < E) {
        // tail (last partial block only): handle fully inline, cold path
        bool is64 = sniff_is64(edges);
        for (int i = 0; i < EPT && e0 + i < E; i++) {
            int sv, dv;
            if (is64) {
                const long long* p = (const long long*)edges;
                sv = (int)p[e0 + i];
                dv = (int)p[(size_t)E + e0 + i];
            } else {
                const int* p = (const int*)edges;
                sv = p[e0 + i];
                dv = p[E + e0 + i];
            }
            int rr = atomicAdd(counts + dv, 1);
            if (rr < CAP) {
                slots[((size_t)dv << 6) + rr] = sv;
            } else {
                int p2 = atomicAdd(oflow_cnt, 1);
                oflow[p2] = make_int2(sv, dv);
            }
        }
    }
    // keep the atomic issue ahead of the mm loads (compiler scheduling fence)
    asm volatile("" ::: "memory");

    // ---------- phase 2: mm tile (64 nodes per block) ----------
    if (bid * 64 < N) {
        int cg = t & 15, g = t >> 4;
        float4 att_d = *(const float4*)&att[cg * 4];        // dst half: att[0:64]
        float4 att_s = *(const float4*)&att[64 + cg * 4];   // src half: att[64:128]

        int n0 = bid * 64 + g * 4;
        int nn[4];
#pragma unroll
        for (int m = 0; m < 4; m++) nn[m] = min(n0 + m, N - 1);

        float4 acc[4];
#pragma unroll
        for (int m = 0; m < 4; m++) acc[m] = make_float4(0.f, 0.f, 0.f, 0.f);

#pragma unroll 2
        for (int k4 = 0; k4 < IN_CH / 4; k4++) {
            float4 xv[4];
#pragma unroll
            for (int m = 0; m < 4; m++)
                xv[m] = *(const float4*)&x[(size_t)nn[m] * IN_CH + k4 * 4];
            float4 wv[4];
#pragma unroll
            for (int j = 0; j < 4; j++)
                wv[j] = *(const float4*)&W[(k4 * 4 + j) * OUT_CH + cg * 4];
#pragma unroll
            for (int m = 0; m < 4; m++) {
                acc[m].x = fmaf(xv[m].x, wv[0].x, acc[m].x);
                acc[m].y = fmaf(xv[m].x, wv[0].y, acc[m].y);
                acc[m].z = fmaf(xv[m].x, wv[0].z, acc[m].z);
                acc[m].w = fmaf(xv[m].x, wv[0].w, acc[m].w);
                acc[m].x = fmaf(xv[m].y, wv[1].x, acc[m].x);
                acc[m].y = fmaf(xv[m].y, wv[1].y, acc[m].y);
                acc[m].z = fmaf(xv[m].y, wv[1].z, acc[m].z);
                acc[m].w = fmaf(xv[m].y, wv[1].w, acc[m].w);
                acc[m].x = fmaf(xv[m].z, wv[2].x, acc[m].x);
                acc[m].y = fmaf(xv[m].z, wv[2].y, acc[m].y);
                acc[m].z = fmaf(xv[m].z, wv[2].z, acc[m].z);
                acc[m].w = fmaf(xv[m].z, wv[2].w, acc[m].w);
                acc[m].x = fmaf(xv[m].w, wv[3].x, acc[m].x);
                acc[m].y = fmaf(xv[m].w, wv[3].y, acc[m].y);
                acc[m].z = fmaf(xv[m].w, wv[3].z, acc[m].z);
                acc[m].w = fmaf(xv[m].w, wv[3].w, acc[m].w);
            }
        }

#pragma unroll
        for (int m = 0; m < 4; m++) {
            int node = n0 + m;
            if (node < N) {
                ushort4 hv;
                hv.x = f2bf(acc[m].x);
                hv.y = f2bf(acc[m].y);
                hv.z = f2bf(acc[m].z);
                hv.w = f2bf(acc[m].w);
                *(ushort4*)&h16[(size_t)node * OUT_CH + cg * 4] = hv;
            }
            float pd = acc[m].x * att_d.x + acc[m].y * att_d.y +
                       acc[m].z * att_d.z + acc[m].w * att_d.w;
            float ps = acc[m].x * att_s.x + acc[m].y * att_s.y +
                       acc[m].z * att_s.z + acc[m].w * att_s.w;
#pragma unroll
            for (int msk = 1; msk < 16; msk <<= 1) {
                pd += __shfl_xor(pd, msk, 64);
                ps += __shfl_xor(ps, msk, 64);
            }
            if (cg == 0 && node < N) { adst[node] = pd; asrc[node] = ps; }
        }
    }

    // ---------- phase 3: slot scatter (atomic results landed under the mm) ----------
    if (fullcs) {
#pragma unroll
        for (int i = 0; i < EPT; i++) {
            if (r[i] < CAP) {
                slots[((size_t)d[i] << 6) + r[i]] = s[i];
            } else {
                int p2 = atomicAdd(oflow_cnt, 1);
                oflow[p2] = make_int2(s[i], d[i]);
            }
        }
    }
}

// ---------- K2: per-node slot-gather softmax-aggregate + bias + L2 normalize ----------
// 1 wave/node, 2 channels/lane (ushort2), half-waves cover 2 src rows per load.
__global__ __launch_bounds__(256) void k_agg(const unsigned short* __restrict__ h16,
                                             const int* __restrict__ slots,
                                             const int* __restrict__ counts,
                                             const int* __restrict__ oflow_cnt,
                                             const int2* __restrict__ oflow,
                                             const float* __restrict__ asrc,
                                             const float* __restrict__ adst,
                                             const float* __restrict__ bias,
                                             float* __restrict__ out, int N) {
    __shared__ float2 stage[4][64];   // wave-private
    int lane = threadIdx.x & 63;
    int wid = threadIdx.x >> 6;
    int node = blockIdx.x * 4 + wid;
    if (node >= N) return;
    int half = lane >> 5;
    int ch2 = (lane & 31) * 2;

    float aD = adst[node];
    // analytic self loop (h row counted in half 0 only)
    float a = aD + asrc[node];
    a = a > 0.f ? a : NEG_SLOPE * a;
    float w_self = __expf(a);
    unsigned hv = *(const unsigned*)&h16[(size_t)node * OUT_CH + ch2];
    float wse = half ? 0.f : w_self;
    float accx = wse * __uint_as_float(hv << 16);
    float accy = wse * __uint_as_float(hv & 0xFFFF0000u);

    int c = counts[node];           // true degree (may exceed CAP)
    int cs = min(c, CAP);
    int sv = 0;
    float wv = 0.f;
    if (lane < cs) {
        sv = slots[((size_t)node << 6) + lane];   // coalesced 256B
        float av = aD + asrc[sv];                 // parallel gather (L2-hot)
        av = av > 0.f ? av : NEG_SLOPE * av;
        wv = __expf(av);                          // once per edge
    }
    float esum_lane = wv;
    stage[wid][lane] = make_float2(__int_as_float(sv), wv);

    for (int j = 0; j < cs; j += 16) {
#pragma unroll
        for (int k = 0; k < 8; k++) {
            float2 p = stage[wid][j + 2 * k + half];   // 2-addr broadcast, free
            int s = __float_as_int(p.x);
            unsigned v = *(const unsigned*)&h16[((size_t)s << 6) + ch2];
            accx = fmaf(p.y, __uint_as_float(v << 16), accx);
            accy = fmaf(p.y, __uint_as_float(v & 0xFFFF0000u), accy);
        }
    }
    // combine half-waves (even rows in lanes 0-31, odd rows in 32-63)
    accx += __shfl_xor(accx, 32, 64);
    accy += __shfl_xor(accy, 32, 64);
#pragma unroll
    for (int m = 32; m >= 1; m >>= 1) esum_lane += __shfl_xor(esum_lane, m, 64);
    float esum = esum_lane + w_self;

    // cold overflow path (oc == 0 for this input; correct if not)
    int oc = *oflow_cnt;
    if (oc > 0) {
        for (int i = 0; i < oc; i++) {
            int2 e = oflow[i];
            if (e.y == node) {
                float av = aD + asrc[e.x];
                av = av > 0.f ? av : NEG_SLOPE * av;
                float w = __expf(av);
                esum += w;
                unsigned v = *(const unsigned*)&h16[((size_t)e.x << 6) + ch2];
                accx = fmaf(w, __uint_as_float(v << 16), accx);
                accy = fmaf(w, __uint_as_float(v & 0xFFFF0000u), accy);
            }
        }
    }

    float inv = 1.f / (esum + 1e-16f);
    float2 bv = *(const float2*)&bias[ch2];
    float vx = accx * inv + bv.x;
    float vy = accy * inv + bv.y;
    float ss = vx * vx + vy * vy;
#pragma unroll
    for (int m = 16; m >= 1; m >>= 1) ss += __shfl_xor(ss, m, 64);   // within half
    float rinv = 1.f / fmaxf(sqrtf(ss), 1e-12f);
    if (!half)
        *(float2*)&out[(size_t)node * OUT_CH + ch2] = make_float2(vx * rinv, vy * rinv);
}

extern "C" void kernel_launch(void* const* d_in, const int* in_sizes, int n_in,
                              void* d_out, int out_size, void* d_ws, size_t ws_size,
                              hipStream_t stream) {
    const float* x    = (const float*)d_in[0];
    const void*  edges = d_in[1];
    const float* W    = (const float*)d_in[2];
    const float* att  = (const float*)d_in[3];
    const float* bias = (const float*)d_in[4];
    float* out = (float*)d_out;

    const int N = in_sizes[0] / IN_CH;
    const int E = in_sizes[1] / 2;
    const int MMB = (N + 63) / 64;                       // mm tiles
    const int CSB = (E + 256 * EPT - 1) / (256 * EPT);   // edge coverage
    const int NB = MMB > CSB ? MMB : CSB;                // 782 == 782 here

    char* ws = (char*)d_ws;
    size_t off = 0;
    auto alloc = [&](size_t bytes) -> void* {
        void* p = ws + off;
        off += bytes;
        off = (off + 255) & ~(size_t)255;
        return p;
    };
    int*            counts   = (int*)alloc((size_t)(N + 64) * 4);  // +oflow_cnt tail
    int*            slots    = (int*)alloc((size_t)N * CAP * 4);   // 12.8 MB
    int2*           oflow    = (int2*)alloc((size_t)E * 8);        // never used in practice
    unsigned short* h16      = (unsigned short*)alloc((size_t)N * OUT_CH * 2);
    float*          asrc     = (float*)alloc((size_t)N * 4);
    float*          adst     = (float*)alloc((size_t)N * 4);
    int*            oflow_cnt = counts + N;

    hipMemsetAsync(counts, 0, (size_t)(N + 64) * 4, stream);
    k_mm_cs<<<NB, 256, 0, stream>>>(x, W, att, h16, asrc, adst, N,
                                    edges, counts, slots, oflow_cnt, oflow, E);
    k_agg<<<(N + 3) / 4, 256, 0, stream>>>(h16, slots, counts, oflow_cnt, oflow,
                                           asrc, adst, bias, out, N);
}

// Round 2
// 162.330 us; speedup vs baseline: 1.0630x; 1.0630x over previous
//
#include <hip/hip_runtime.h>
#include <math.h>

#define IN_CH 128
#define OUT_CH 64
#define NEG_SLOPE 0.2f
#define CAP 64   // slots per node; mean degree 16, P(deg>64) ~ 1e-16 for uniform dst
#define EPT 2    // edges per thread (count+scatter) -> CSB=1563 blocks for latency hiding

typedef long long ll2 __attribute__((ext_vector_type(2)));
typedef int i2v __attribute__((ext_vector_type(2)));

// ---------- bf16 helpers ----------
__device__ __forceinline__ unsigned short f2bf(float f) {
    unsigned u = __float_as_uint(f);
    unsigned r = (u + 0x7FFFu + ((u >> 16) & 1u)) >> 16;   // round-nearest-even
    return (unsigned short)r;
}

// ---------- edge dtype sniff: int64 little-endian => odd int32 words are 0 ----------
__device__ __forceinline__ bool sniff_is64(const void* edges) {
    const unsigned* up = (const unsigned*)edges;
    bool is64 = true;
#pragma unroll
    for (int k = 0; k < 16; k++) is64 = is64 && (up[2 * k + 1] == 0u);
    return is64;
}

// ---------- K1 (role-split, interleaved): even blocks mm, odd blocks count+scatter ----
// R1 lesson: fusing cs under mm HALVED the grid (782 blocks = 3/CU) and regressed
// 59->80us. The atomic/scatter round trips (~800cy) are hidden by CO-RESIDENT WAVES,
// not intra-wave overlap. So: role-split (mm waves give the CU VALU work while cs
// waves sit in vmcnt waits), NO LDS anywhere (old 32KB Ws capped cs blocks at 5/CU),
// EPT=2 so the cs grid doubles vs R0: 782 mm + 1563 cs = 2345 blocks ~ 9.2/CU.
// cs edge reads stay NON-TEMPORAL (R12 evidence: streaming edge columns otherwise
// evict dirty slot lines mid-accumulation).
__global__ __launch_bounds__(256) void k_mm_cs(
        const float* __restrict__ x, const float* __restrict__ W,
        const float* __restrict__ att, unsigned short* __restrict__ h16,
        float* __restrict__ asrc, float* __restrict__ adst, int N,
        const void* __restrict__ edges, int* __restrict__ counts,
        int* __restrict__ slots, int* __restrict__ oflow_cnt,
        int2* __restrict__ oflow, int E, int mmb, int csb) {
    int t = threadIdx.x;
    int bid = blockIdx.x;
    int lo = min(mmb, csb), M2 = 2 * lo;
    int role, id;   // role 0 = mm, 1 = count+scatter
    if (bid < M2) { role = bid & 1; id = bid >> 1; }
    else          { role = (mmb > csb) ? 0 : 1; id = bid - M2 + lo; }

    if (role == 1) {
        // ----- count+scatter: EPT=2 edges/thread, nt loads, atomic -> slot store -----
        int e0 = (id * 256 + t) * EPT;
        if (e0 >= E) return;
        bool full = (e0 + 1 < E);
        int s[2], d[2];
        if (full) {
            if (sniff_is64(edges)) {
                ll2 v = __builtin_nontemporal_load(
                    (const ll2*)((const long long*)edges + e0));
                ll2 w = __builtin_nontemporal_load(
                    (const ll2*)((const long long*)edges + (size_t)E + e0));
                s[0] = (int)v.x; s[1] = (int)v.y;
                d[0] = (int)w.x; d[1] = (int)w.y;
            } else {
                i2v v = __builtin_nontemporal_load(
                    (const i2v*)((const int*)edges + e0));
                i2v w = __builtin_nontemporal_load(
                    (const i2v*)((const int*)edges + E + e0));
                s[0] = v.x; s[1] = v.y;
                d[0] = w.x; d[1] = w.y;
            }
            int r0 = atomicAdd(counts + d[0], 1);
            int r1 = atomicAdd(counts + d[1], 1);
            if (r0 < CAP) {
                slots[((size_t)d[0] << 6) + r0] = s[0];
            } else {
                int p2 = atomicAdd(oflow_cnt, 1);
                oflow[p2] = make_int2(s[0], d[0]);
            }
            if (r1 < CAP) {
                slots[((size_t)d[1] << 6) + r1] = s[1];
            } else {
                int p2 = atomicAdd(oflow_cnt, 1);
                oflow[p2] = make_int2(s[1], d[1]);
            }
        } else {
            // tail: single edge (cold path)
            int sv, dv;
            if (sniff_is64(edges)) {
                const long long* p = (const long long*)edges;
                sv = (int)p[e0];
                dv = (int)p[(size_t)E + e0];
            } else {
                const int* p = (const int*)edges;
                sv = p[e0];
                dv = p[E + e0];
            }
            int rr = atomicAdd(counts + dv, 1);
            if (rr < CAP) {
                slots[((size_t)dv << 6) + rr] = sv;
            } else {
                int p2 = atomicAdd(oflow_cnt, 1);
                oflow[p2] = make_int2(sv, dv);
            }
        }
        return;
    }

    // ----- mm path: 64 nodes/block, W straight from global (L1/L2-resident 32KB) -----
    int cg = t & 15, g = t >> 4;
    float4 att_d = *(const float4*)&att[cg * 4];        // dst half: att[0:64]
    float4 att_s = *(const float4*)&att[64 + cg * 4];   // src half: att[64:128]

    int n0 = id * 64 + g * 4;
    int nn[4];
#pragma unroll
    for (int m = 0; m < 4; m++) nn[m] = min(n0 + m, N - 1);

    float4 acc[4];
#pragma unroll
    for (int m = 0; m < 4; m++) acc[m] = make_float4(0.f, 0.f, 0.f, 0.f);

#pragma unroll 2
    for (int k4 = 0; k4 < IN_CH / 4; k4++) {
        float4 xv[4];
#pragma unroll
        for (int m = 0; m < 4; m++)
            xv[m] = *(const float4*)&x[(size_t)nn[m] * IN_CH + k4 * 4];
        float4 wv[4];
#pragma unroll
        for (int j = 0; j < 4; j++)
            wv[j] = *(const float4*)&W[(k4 * 4 + j) * OUT_CH + cg * 4];
#pragma unroll
        for (int m = 0; m < 4; m++) {
            acc[m].x = fmaf(xv[m].x, wv[0].x, acc[m].x);
            acc[m].y = fmaf(xv[m].x, wv[0].y, acc[m].y);
            acc[m].z = fmaf(xv[m].x, wv[0].z, acc[m].z);
            acc[m].w = fmaf(xv[m].x, wv[0].w, acc[m].w);
            acc[m].x = fmaf(xv[m].y, wv[1].x, acc[m].x);
            acc[m].y = fmaf(xv[m].y, wv[1].y, acc[m].y);
            acc[m].z = fmaf(xv[m].y, wv[1].z, acc[m].z);
            acc[m].w = fmaf(xv[m].y, wv[1].w, acc[m].w);
            acc[m].x = fmaf(xv[m].z, wv[2].x, acc[m].x);
            acc[m].y = fmaf(xv[m].z, wv[2].y, acc[m].y);
            acc[m].z = fmaf(xv[m].z, wv[2].z, acc[m].z);
            acc[m].w = fmaf(xv[m].z, wv[2].w, acc[m].w);
            acc[m].x = fmaf(xv[m].w, wv[3].x, acc[m].x);
            acc[m].y = fmaf(xv[m].w, wv[3].y, acc[m].y);
            acc[m].z = fmaf(xv[m].w, wv[3].z, acc[m].z);
            acc[m].w = fmaf(xv[m].w, wv[3].w, acc[m].w);
        }
    }

#pragma unroll
    for (int m = 0; m < 4; m++) {
        int node = n0 + m;
        if (node < N) {
            ushort4 hv;
            hv.x = f2bf(acc[m].x);
            hv.y = f2bf(acc[m].y);
            hv.z = f2bf(acc[m].z);
            hv.w = f2bf(acc[m].w);
            *(ushort4*)&h16[(size_t)node * OUT_CH + cg * 4] = hv;
        }
        float pd = acc[m].x * att_d.x + acc[m].y * att_d.y +
                   acc[m].z * att_d.z + acc[m].w * att_d.w;
        float ps = acc[m].x * att_s.x + acc[m].y * att_s.y +
                   acc[m].z * att_s.z + acc[m].w * att_s.w;
#pragma unroll
        for (int msk = 1; msk < 16; msk <<= 1) {
            pd += __shfl_xor(pd, msk, 64);
            ps += __shfl_xor(ps, msk, 64);
        }
        if (cg == 0 && node < N) { adst[node] = pd; asrc[node] = ps; }
    }
}

// ---------- K2: per-node slot-gather softmax-aggregate + bias + L2 normalize ----------
// 1 wave/node, 2 channels/lane (ushort2), half-waves cover 2 src rows per load.
__global__ __launch_bounds__(256) void k_agg(const unsigned short* __restrict__ h16,
                                             const int* __restrict__ slots,
                                             const int* __restrict__ counts,
                                             const int* __restrict__ oflow_cnt,
                                             const int2* __restrict__ oflow,
                                             const float* __restrict__ asrc,
                                             const float* __restrict__ adst,
                                             const float* __restrict__ bias,
                                             float* __restrict__ out, int N) {
    __shared__ float2 stage[4][64];   // wave-private
    int lane = threadIdx.x & 63;
    int wid = threadIdx.x >> 6;
    int node = blockIdx.x * 4 + wid;
    if (node >= N) return;
    int half = lane >> 5;
    int ch2 = (lane & 31) * 2;

    float aD = adst[node];
    // analytic self loop (h row counted in half 0 only)
    float a = aD + asrc[node];
    a = a > 0.f ? a : NEG_SLOPE * a;
    float w_self = __expf(a);
    unsigned hv = *(const unsigned*)&h16[(size_t)node * OUT_CH + ch2];
    float wse = half ? 0.f : w_self;
    float accx = wse * __uint_as_float(hv << 16);
    float accy = wse * __uint_as_float(hv & 0xFFFF0000u);

    int c = counts[node];           // true degree (may exceed CAP)
    int cs = min(c, CAP);
    int sv = 0;
    float wv = 0.f;
    if (lane < cs) {
        sv = slots[((size_t)node << 6) + lane];   // coalesced 256B
        float av = aD + asrc[sv];                 // parallel gather (L2-hot)
        av = av > 0.f ? av : NEG_SLOPE * av;
        wv = __expf(av);                          // once per edge
    }
    float esum_lane = wv;
    stage[wid][lane] = make_float2(__int_as_float(sv), wv);

    for (int j = 0; j < cs; j += 16) {
#pragma unroll
        for (int k = 0; k < 8; k++) {
            float2 p = stage[wid][j + 2 * k + half];   // 2-addr broadcast, free
            int s = __float_as_int(p.x);
            unsigned v = *(const unsigned*)&h16[((size_t)s << 6) + ch2];
            accx = fmaf(p.y, __uint_as_float(v << 16), accx);
            accy = fmaf(p.y, __uint_as_float(v & 0xFFFF0000u), accy);
        }
    }
    // combine half-waves (even rows in lanes 0-31, odd rows in 32-63)
    accx += __shfl_xor(accx, 32, 64);
    accy += __shfl_xor(accy, 32, 64);
#pragma unroll
    for (int m = 32; m >= 1; m >>= 1) esum_lane += __shfl_xor(esum_lane, m, 64);
    float esum = esum_lane + w_self;

    // cold overflow path (oc == 0 for this input; correct if not)
    int oc = *oflow_cnt;
    if (oc > 0) {
        for (int i = 0; i < oc; i++) {
            int2 e = oflow[i];
            if (e.y == node) {
                float av = aD + asrc[e.x];
                av = av > 0.f ? av : NEG_SLOPE * av;
                float w = __expf(av);
                esum += w;
                unsigned v = *(const unsigned*)&h16[((size_t)e.x << 6) + ch2];
                accx = fmaf(w, __uint_as_float(v << 16), accx);
                accy = fmaf(w, __uint_as_float(v & 0xFFFF0000u), accy);
            }
        }
    }

    float inv = 1.f / (esum + 1e-16f);
    float2 bv = *(const float2*)&bias[ch2];
    float vx = accx * inv + bv.x;
    float vy = accy * inv + bv.y;
    float ss = vx * vx + vy * vy;
#pragma unroll
    for (int m = 16; m >= 1; m >>= 1) ss += __shfl_xor(ss, m, 64);   // within half
    float rinv = 1.f / fmaxf(sqrtf(ss), 1e-12f);
    if (!half)
        *(float2*)&out[(size_t)node * OUT_CH + ch2] = make_float2(vx * rinv, vy * rinv);
}

extern "C" void kernel_launch(void* const* d_in, const int* in_sizes, int n_in,
                              void* d_out, int out_size, void* d_ws, size_t ws_size,
                              hipStream_t stream) {
    const float* x    = (const float*)d_in[0];
    const void*  edges = d_in[1];
    const float* W    = (const float*)d_in[2];
    const float* att  = (const float*)d_in[3];
    const float* bias = (const float*)d_in[4];
    float* out = (float*)d_out;

    const int N = in_sizes[0] / IN_CH;
    const int E = in_sizes[1] / 2;
    const int MMB = (N + 63) / 64;                       // mm blocks (782)
    const int CSB = (E + 256 * EPT - 1) / (256 * EPT);   // cs blocks (1563 @ EPT=2)

    char* ws = (char*)d_ws;
    size_t off = 0;
    auto alloc = [&](size_t bytes) -> void* {
        void* p = ws + off;
        off += bytes;
        off = (off + 255) & ~(size_t)255;
        return p;
    };
    int*            counts   = (int*)alloc((size_t)(N + 64) * 4);  // +oflow_cnt tail
    int*            slots    = (int*)alloc((size_t)N * CAP * 4);   // 12.8 MB
    int2*           oflow    = (int2*)alloc((size_t)E * 8);        // never used in practice
    unsigned short* h16      = (unsigned short*)alloc((size_t)N * OUT_CH * 2);
    float*          asrc     = (float*)alloc((size_t)N * 4);
    float*          adst     = (float*)alloc((size_t)N * 4);
    int*            oflow_cnt = counts + N;

    hipMemsetAsync(counts, 0, (size_t)(N + 64) * 4, stream);
    k_mm_cs<<<MMB + CSB, 256, 0, stream>>>(x, W, att, h16, asrc, adst, N,
                                           edges, counts, slots, oflow_cnt,
                                           oflow, E, MMB, CSB);
    k_agg<<<(N + 3) / 4, 256, 0, stream>>>(h16, slots, counts, oflow_cnt, oflow,
                                           asrc, adst, bias, out, N);
}

// Round 3
// 155.994 us; speedup vs baseline: 1.1062x; 1.0406x over previous
//
#include <hip/hip_runtime.h>
#include <math.h>

#define IN_CH 128
#define OUT_CH 64
#define NEG_SLOPE 0.2f
#define CAP 64   // slots per node; mean degree 16, P(deg>64) ~ 1e-16 for uniform dst
#define EPT 8    // edges per thread: 8 fire-and-forget atomics in flight per lane

typedef long long ll2 __attribute__((ext_vector_type(2)));
typedef int i4v __attribute__((ext_vector_type(4)));

// ---------- bf16 helpers ----------
__device__ __forceinline__ unsigned short f2bf(float f) {
    unsigned u = __float_as_uint(f);
    unsigned r = (u + 0x7FFFu + ((u >> 16) & 1u)) >> 16;   // round-nearest-even
    return (unsigned short)r;
}

// ---------- edge dtype sniff: int64 little-endian => odd int32 words are 0 ----------
__device__ __forceinline__ bool sniff_is64(const void* edges) {
    const unsigned* up = (const unsigned*)edges;
    bool is64 = true;
#pragma unroll
    for (int k = 0; k < 16; k++) is64 = is64 && (up[2 * k + 1] == 0u);
    return is64;
}

// ---------- K1 (role-split, Bresenham-interleaved): mm blocks + count+scatter blocks --
// R0<->R2 A/B evidence: cs path is ATOMIC-LATENCY-bound and scales with PER-LANE
// outstanding atomics (EPT=4 -> 59us total, EPT=2 -> 78us), NOT with block count
// (2345 blocks didn't help; occupancy stuck ~25% either way). So EPT=8: 8 nt edge
// loads -> 8 independent atomicAdd in flight -> 8 dependent slot stores.
// W is LDS-staged in mm blocks (R2 removing it cost VALU efficiency); at 1173 total
// blocks (4.6/CU) the 32KB/block LDS cap of 5 blocks/CU is not binding.
// cs edge reads stay NON-TEMPORAL (streaming edge columns otherwise evict dirty
// slot lines mid-accumulation; prior-session R12 evidence).
__global__ __launch_bounds__(256) void k_mm_cs(
        const float* __restrict__ x, const float* __restrict__ W,
        const float* __restrict__ att, unsigned short* __restrict__ h16,
        float* __restrict__ asrc, float* __restrict__ adst, int N,
        const void* __restrict__ edges, int* __restrict__ counts,
        int* __restrict__ slots, int* __restrict__ oflow_cnt,
        int2* __restrict__ oflow, int E, int mmb, int csb) {
    __shared__ float Ws[IN_CH * OUT_CH];   // 32 KB (mm role only)
    int t = threadIdx.x;
    int bid = blockIdx.x;
    int total = mmb + csb;
    // Bresenham spread: cs blocks evenly distributed through the grid (1:2 here)
    int cbefore = (int)(((long long)bid * csb) / total);
    int cafter  = (int)(((long long)(bid + 1) * csb) / total);
    int role = (cafter != cbefore) ? 1 : 0;
    int id = role ? cbefore : (bid - cbefore);

    if (role == 1) {
        // ----- count+scatter: EPT=8, nt loads, 8-deep atomic pipeline -----
        int e0 = (id * 256 + t) * EPT;
        if (e0 >= E) return;
        int s[EPT], d[EPT], r[EPT];
        if (e0 + EPT <= E) {
            if (sniff_is64(edges)) {
                const ll2* ps = (const ll2*)((const long long*)edges + e0);
                const ll2* pd = (const ll2*)((const long long*)edges + (size_t)E + e0);
#pragma unroll
                for (int i = 0; i < EPT / 2; i++) {
                    ll2 v = __builtin_nontemporal_load(ps + i);
                    s[2 * i] = (int)v.x; s[2 * i + 1] = (int)v.y;
                }
#pragma unroll
                for (int i = 0; i < EPT / 2; i++) {
                    ll2 w = __builtin_nontemporal_load(pd + i);
                    d[2 * i] = (int)w.x; d[2 * i + 1] = (int)w.y;
                }
            } else {
                const i4v* ps = (const i4v*)((const int*)edges + e0);
                const i4v* pd = (const i4v*)((const int*)edges + E + e0);
#pragma unroll
                for (int i = 0; i < EPT / 4; i++) {
                    i4v v = __builtin_nontemporal_load(ps + i);
                    s[4 * i] = v.x; s[4 * i + 1] = v.y;
                    s[4 * i + 2] = v.z; s[4 * i + 3] = v.w;
                }
#pragma unroll
                for (int i = 0; i < EPT / 4; i++) {
                    i4v w = __builtin_nontemporal_load(pd + i);
                    d[4 * i] = w.x; d[4 * i + 1] = w.y;
                    d[4 * i + 2] = w.z; d[4 * i + 3] = w.w;
                }
            }
            // all 8 atomics issued before any result is consumed (8-deep MLP)
#pragma unroll
            for (int i = 0; i < EPT; i++) r[i] = atomicAdd(counts + d[i], 1);
#pragma unroll
            for (int i = 0; i < EPT; i++) {
                if (r[i] < CAP) {
                    slots[((size_t)d[i] << 6) + r[i]] = s[i];
                } else {
                    int p2 = atomicAdd(oflow_cnt, 1);
                    oflow[p2] = make_int2(s[i], d[i]);
                }
            }
        } else {
            // tail (cold): per-edge
            bool is64 = sniff_is64(edges);
            for (int i = 0; i < EPT && e0 + i < E; i++) {
                int sv, dv;
                if (is64) {
                    const long long* p = (const long long*)edges;
                    sv = (int)p[e0 + i];
                    dv = (int)p[(size_t)E + e0 + i];
                } else {
                    const int* p = (const int*)edges;
                    sv = p[e0 + i];
                    dv = p[E + e0 + i];
                }
                int rr = atomicAdd(counts + dv, 1);
                if (rr < CAP) {
                    slots[((size_t)dv << 6) + rr] = sv;
                } else {
                    int p2 = atomicAdd(oflow_cnt, 1);
                    oflow[p2] = make_int2(sv, dv);
                }
            }
        }
        return;
    }

    // ----- mm path: 64 nodes/block, W staged in LDS -----
    for (int i = t * 4; i < IN_CH * OUT_CH; i += 256 * 4)
        *(float4*)&Ws[i] = *(const float4*)&W[i];
    int cg = t & 15, g = t >> 4;
    float4 att_d = *(const float4*)&att[cg * 4];        // dst half: att[0:64]
    float4 att_s = *(const float4*)&att[64 + cg * 4];   // src half: att[64:128]
    __syncthreads();

    int n0 = id * 64 + g * 4;
    int nn[4];
#pragma unroll
    for (int m = 0; m < 4; m++) nn[m] = min(n0 + m, N - 1);

    float4 acc[4];
#pragma unroll
    for (int m = 0; m < 4; m++) acc[m] = make_float4(0.f, 0.f, 0.f, 0.f);

#pragma unroll 2
    for (int k4 = 0; k4 < IN_CH / 4; k4++) {
        float4 xv[4];
#pragma unroll
        for (int m = 0; m < 4; m++)
            xv[m] = *(const float4*)&x[(size_t)nn[m] * IN_CH + k4 * 4];
        float4 wv[4];
#pragma unroll
        for (int j = 0; j < 4; j++)
            wv[j] = *(const float4*)&Ws[(k4 * 4 + j) * OUT_CH + cg * 4];
#pragma unroll
        for (int m = 0; m < 4; m++) {
            acc[m].x = fmaf(xv[m].x, wv[0].x, acc[m].x);
            acc[m].y = fmaf(xv[m].x, wv[0].y, acc[m].y);
            acc[m].z = fmaf(xv[m].x, wv[0].z, acc[m].z);
            acc[m].w = fmaf(xv[m].x, wv[0].w, acc[m].w);
            acc[m].x = fmaf(xv[m].y, wv[1].x, acc[m].x);
            acc[m].y = fmaf(xv[m].y, wv[1].y, acc[m].y);
            acc[m].z = fmaf(xv[m].y, wv[1].z, acc[m].z);
            acc[m].w = fmaf(xv[m].y, wv[1].w, acc[m].w);
            acc[m].x = fmaf(xv[m].z, wv[2].x, acc[m].x);
            acc[m].y = fmaf(xv[m].z, wv[2].y, acc[m].y);
            acc[m].z = fmaf(xv[m].z, wv[2].z, acc[m].z);
            acc[m].w = fmaf(xv[m].z, wv[2].w, acc[m].w);
            acc[m].x = fmaf(xv[m].w, wv[3].x, acc[m].x);
            acc[m].y = fmaf(xv[m].w, wv[3].y, acc[m].y);
            acc[m].z = fmaf(xv[m].w, wv[3].z, acc[m].z);
            acc[m].w = fmaf(xv[m].w, wv[3].w, acc[m].w);
        }
    }

#pragma unroll
    for (int m = 0; m < 4; m++) {
        int node = n0 + m;
        if (node < N) {
            ushort4 hv;
            hv.x = f2bf(acc[m].x);
            hv.y = f2bf(acc[m].y);
            hv.z = f2bf(acc[m].z);
            hv.w = f2bf(acc[m].w);
            *(ushort4*)&h16[(size_t)node * OUT_CH + cg * 4] = hv;
        }
        float pd = acc[m].x * att_d.x + acc[m].y * att_d.y +
                   acc[m].z * att_d.z + acc[m].w * att_d.w;
        float ps = acc[m].x * att_s.x + acc[m].y * att_s.y +
                   acc[m].z * att_s.z + acc[m].w * att_s.w;
#pragma unroll
        for (int msk = 1; msk < 16; msk <<= 1) {
            pd += __shfl_xor(pd, msk, 64);
            ps += __shfl_xor(ps, msk, 64);
        }
        if (cg == 0 && node < N) { adst[node] = pd; asrc[node] = ps; }
    }
}

// ---------- K2: per-node slot-gather softmax-aggregate + bias + L2 normalize ----------
// 1 wave/node, 2 channels/lane (ushort2), half-waves cover 2 src rows per load.
__global__ __launch_bounds__(256) void k_agg(const unsigned short* __restrict__ h16,
                                             const int* __restrict__ slots,
                                             const int* __restrict__ counts,
                                             const int* __restrict__ oflow_cnt,
                                             const int2* __restrict__ oflow,
                                             const float* __restrict__ asrc,
                                             const float* __restrict__ adst,
                                             const float* __restrict__ bias,
                                             float* __restrict__ out, int N) {
    __shared__ float2 stage[4][64];   // wave-private
    int lane = threadIdx.x & 63;
    int wid = threadIdx.x >> 6;
    int node = blockIdx.x * 4 + wid;
    if (node >= N) return;
    int half = lane >> 5;
    int ch2 = (lane & 31) * 2;

    float aD = adst[node];
    // analytic self loop (h row counted in half 0 only)
    float a = aD + asrc[node];
    a = a > 0.f ? a : NEG_SLOPE * a;
    float w_self = __expf(a);
    unsigned hv = *(const unsigned*)&h16[(size_t)node * OUT_CH + ch2];
    float wse = half ? 0.f : w_self;
    float accx = wse * __uint_as_float(hv << 16);
    float accy = wse * __uint_as_float(hv & 0xFFFF0000u);

    int c = counts[node];           // true degree (may exceed CAP)
    int cs = min(c, CAP);
    int sv = 0;
    float wv = 0.f;
    if (lane < cs) {
        sv = slots[((size_t)node << 6) + lane];   // coalesced 256B
        float av = aD + asrc[sv];                 // parallel gather (L2-hot)
        av = av > 0.f ? av : NEG_SLOPE * av;
        wv = __expf(av);                          // once per edge
    }
    float esum_lane = wv;
    stage[wid][lane] = make_float2(__int_as_float(sv), wv);

    for (int j = 0; j < cs; j += 16) {
#pragma unroll
        for (int k = 0; k < 8; k++) {
            float2 p = stage[wid][j + 2 * k + half];   // 2-addr broadcast, free
            int s = __float_as_int(p.x);
            unsigned v = *(const unsigned*)&h16[((size_t)s << 6) + ch2];
            accx = fmaf(p.y, __uint_as_float(v << 16), accx);
            accy = fmaf(p.y, __uint_as_float(v & 0xFFFF0000u), accy);
        }
    }
    // combine half-waves (even rows in lanes 0-31, odd rows in 32-63)
    accx += __shfl_xor(accx, 32, 64);
    accy += __shfl_xor(accy, 32, 64);
#pragma unroll
    for (int m = 32; m >= 1; m >>= 1) esum_lane += __shfl_xor(esum_lane, m, 64);
    float esum = esum_lane + w_self;

    // cold overflow path (oc == 0 for this input; correct if not)
    int oc = *oflow_cnt;
    if (oc > 0) {
        for (int i = 0; i < oc; i++) {
            int2 e = oflow[i];
            if (e.y == node) {
                float av = aD + asrc[e.x];
                av = av > 0.f ? av : NEG_SLOPE * av;
                float w = __expf(av);
                esum += w;
                unsigned v = *(const unsigned*)&h16[((size_t)e.x << 6) + ch2];
                accx = fmaf(w, __uint_as_float(v << 16), accx);
                accy = fmaf(w, __uint_as_float(v & 0xFFFF0000u), accy);
            }
        }
    }

    float inv = 1.f / (esum + 1e-16f);
    float2 bv = *(const float2*)&bias[ch2];
    float vx = accx * inv + bv.x;
    float vy = accy * inv + bv.y;
    float ss = vx * vx + vy * vy;
#pragma unroll
    for (int m = 16; m >= 1; m >>= 1) ss += __shfl_xor(ss, m, 64);   // within half
    float rinv = 1.f / fmaxf(sqrtf(ss), 1e-12f);
    if (!half)
        *(float2*)&out[(size_t)node * OUT_CH + ch2] = make_float2(vx * rinv, vy * rinv);
}

extern "C" void kernel_launch(void* const* d_in, const int* in_sizes, int n_in,
                              void* d_out, int out_size, void* d_ws, size_t ws_size,
                              hipStream_t stream) {
    const float* x    = (const float*)d_in[0];
    const void*  edges = d_in[1];
    const float* W    = (const float*)d_in[2];
    const float* att  = (const float*)d_in[3];
    const float* bias = (const float*)d_in[4];
    float* out = (float*)d_out;

    const int N = in_sizes[0] / IN_CH;
    const int E = in_sizes[1] / 2;
    const int MMB = (N + 63) / 64;                       // mm blocks (782)
    const int CSB = (E + 256 * EPT - 1) / (256 * EPT);   // cs blocks (391 @ EPT=8)

    char* ws = (char*)d_ws;
    size_t off = 0;
    auto alloc = [&](size_t bytes) -> void* {
        void* p = ws + off;
        off += bytes;
        off = (off + 255) & ~(size_t)255;
        return p;
    };
    int*            counts   = (int*)alloc((size_t)(N + 64) * 4);  // +oflow_cnt tail
    int*            slots    = (int*)alloc((size_t)N * CAP * 4);   // 12.8 MB
    int2*           oflow    = (int2*)alloc((size_t)E * 8);        // never used in practice
    unsigned short* h16      = (unsigned short*)alloc((size_t)N * OUT_CH * 2);
    float*          asrc     = (float*)alloc((size_t)N * 4);
    float*          adst     = (float*)alloc((size_t)N * 4);
    int*            oflow_cnt = counts + N;

    hipMemsetAsync(counts, 0, (size_t)(N + 64) * 4, stream);
    k_mm_cs<<<MMB + CSB, 256, 0, stream>>>(x, W, att, h16, asrc, adst, N,
                                           edges, counts, slots, oflow_cnt,
                                           oflow, E, MMB, CSB);
    k_agg<<<(N + 3) / 4, 256, 0, stream>>>(h16, slots, counts, oflow_cnt, oflow,
                                           asrc, adst, bias, out, N);
}